// Round 9
// baseline (391.495 us; speedup 1.0000x reference)
//
#include <hip/hip_runtime.h>

// GraphConvolution: out = A_coo @ (x @ W)
// x: [100000, 256] f32, W: [256, 64] f32, A: 1.6M edges (rows, cols int32, vals f32)
//
// R8 -> R9: gemm_xw was the measured top (97us, VALUBusy 27%, LDS-instr-bound:
// 12 b128 reads / 128 FMA = 1.5B/FMA). Rebuilt: 8x8 thread tile (1.0B/FMA),
// BK=16, global_load_lds(16B) staging with pre-swizzled source, double-buffered
// LDS, stage-before-compute pipeline. spmm_reduce unroll 4->8 (orthogonal,
// separable per-dispatch).

#define KDIM 256
#define MDIM 64
#define BSHIFT 7              // 128 rows per bucket
#define BMAX 1024             // max buckets supported by LDS tables
#define FCAP 6500             // fine_scatter LDS staging capacity (records)

// ---------------------------------------------------------------- GEMM
__device__ __forceinline__ void gld_lds16(const float* g, float* l) {
    __builtin_amdgcn_global_load_lds(
        (const __attribute__((address_space(1))) unsigned int*)g,
        (__attribute__((address_space(3))) unsigned int*)l, 16, 0, 0);
}

// 256 rows x 64 feats per block, BK=16, dbuf LDS (2 x 20KB), thread tile 8x8.
// xs stored with k-quad slot = kq ^ ((row>>3)&3) (source pre-swizzled so
// global_load_lds dest stays linear); read back with same XOR -> <=2-way
// bank aliasing (free). ws [kk][f] linear: fg pairs 2-way alias only.
__global__ __launch_bounds__(256, 3) void gemm_xw(
    const float* __restrict__ x, const float* __restrict__ W,
    float* __restrict__ support, int nrows)
{
    __shared__ float lds[2][5120];    // per buf: xs 256x16 (4096 f) | ws 16x64 (1024 f)
    const int tid  = threadIdx.x;
    const int lane = tid & 63;
    const int wid  = tid >> 6;        // wave 0..3
    const int rg   = tid >> 3;        // 0..31 row-group
    const int fg   = tid & 7;         // 0..7 feat-group
    const int r0   = rg * 8;
    const int f0   = fg * 8;
    const int sk   = rg & 3;          // xs slot XOR key
    const int row0 = blockIdx.x * 256;

    float acc[8][8];
    #pragma unroll
    for (int i = 0; i < 8; ++i)
        #pragma unroll
        for (int j = 0; j < 8; ++j) acc[i][j] = 0.f;

    auto stage = [&](int bf, int kt) {
        // xs: 16 KB -> 16 instrs, 4 per wave. instr ig covers rows 16ig..16ig+15.
        #pragma unroll
        for (int j = 0; j < 4; ++j) {
            const int ig  = wid * 4 + j;
            const int row = ig * 16 + (lane >> 2);
            const int kq  = (lane & 3) ^ ((row >> 3) & 3);   // pre-swizzled source
            const int gr  = min(row0 + row, nrows - 1);
            gld_lds16(x + (size_t)gr * KDIM + kt + kq * 4,
                      &lds[bf][ig * 256]);
        }
        // ws: 4 KB -> 4 instrs, 1 per wave. instr wid covers kk 4wid..4wid+3.
        {
            const int kk = wid * 4 + (lane >> 4);
            const int fq = lane & 15;
            gld_lds16(W + (size_t)(kt + kk) * MDIM + fq * 4,
                      &lds[bf][4096 + wid * 256]);
        }
    };

    auto compute = [&](int bf) {
        const float* xs = &lds[bf][0];
        const float* ws = &lds[bf][4096];
        #pragma unroll
        for (int q = 0; q < 4; ++q) {          // k-quad within BK=16
            float4 xv[8];
            const int slot = q ^ sk;
            #pragma unroll
            for (int i = 0; i < 8; ++i)
                xv[i] = *reinterpret_cast<const float4*>(
                            &xs[(r0 + i) * 16 + slot * 4]);
            #pragma unroll
            for (int k2 = 0; k2 < 4; ++k2) {
                const int kk = q * 4 + k2;
                const float4 wa = *reinterpret_cast<const float4*>(
                                      &ws[kk * 64 + f0]);
                const float4 wb = *reinterpret_cast<const float4*>(
                                      &ws[kk * 64 + f0 + 4]);
                #pragma unroll
                for (int i = 0; i < 8; ++i) {
                    const float xk = (k2 == 0) ? xv[i].x :
                                     (k2 == 1) ? xv[i].y :
                                     (k2 == 2) ? xv[i].z : xv[i].w;
                    acc[i][0] = fmaf(xk, wa.x, acc[i][0]);
                    acc[i][1] = fmaf(xk, wa.y, acc[i][1]);
                    acc[i][2] = fmaf(xk, wa.z, acc[i][2]);
                    acc[i][3] = fmaf(xk, wa.w, acc[i][3]);
                    acc[i][4] = fmaf(xk, wb.x, acc[i][4]);
                    acc[i][5] = fmaf(xk, wb.y, acc[i][5]);
                    acc[i][6] = fmaf(xk, wb.z, acc[i][6]);
                    acc[i][7] = fmaf(xk, wb.w, acc[i][7]);
                }
            }
        }
    };

    stage(0, 0);
    __syncthreads();                  // drains vmcnt: buf0 ready
    int bf = 0;
    #pragma unroll 1
    for (int t = 0; t < KDIM / 16; ++t) {
        if (t < KDIM / 16 - 1) stage(bf ^ 1, (t + 1) * 16);  // async prefetch
        compute(bf);
        __syncthreads();              // drains prefetch + guards buffer reuse
        bf ^= 1;
    }

    #pragma unroll
    for (int i = 0; i < 8; ++i) {
        const int grow = row0 + r0 + i;
        if (grow < nrows) {
            *reinterpret_cast<float4*>(&support[(size_t)grow * MDIM + f0]) =
                make_float4(acc[i][0], acc[i][1], acc[i][2], acc[i][3]);
            *reinterpret_cast<float4*>(&support[(size_t)grow * MDIM + f0 + 4]) =
                make_float4(acc[i][4], acc[i][5], acc[i][6], acc[i][7]);
        }
    }
}

// ------------------------------------------------- coarse bucket build
__global__ __launch_bounds__(256) void coarse_hist(
    const int* __restrict__ rows, int* __restrict__ counts,
    int nedges, int nbuckets)
{
    __shared__ int lb[BMAX];
    const int t = threadIdx.x;
    for (int i = t; i < nbuckets; i += 256) lb[i] = 0;
    __syncthreads();
    int e = blockIdx.x * 256 + t;
    const int stride = gridDim.x * 256;
    for (; e < nedges; e += stride)
        atomicAdd(&lb[rows[e] >> BSHIFT], 1);
    __syncthreads();
    for (int i = t; i < nbuckets; i += 256) {
        int c = lb[i];
        if (c) atomicAdd(&counts[i], c);
    }
}

// Single-block exclusive scan (n <= 1024): offsets + cursor seed.
__global__ __launch_bounds__(256) void coarse_scan(
    const int* __restrict__ counts, int* __restrict__ offsets,
    int* __restrict__ cursor, int n)
{
    __shared__ int sh[256];
    const int t = threadIdx.x;
    const int base = t * 4;
    int v0 = 0, v1 = 0, v2 = 0, v3 = 0;
    if (base + 0 < n) v0 = counts[base + 0];
    if (base + 1 < n) v1 = counts[base + 1];
    if (base + 2 < n) v2 = counts[base + 2];
    if (base + 3 < n) v3 = counts[base + 3];
    const int tsum = v0 + v1 + v2 + v3;
    sh[t] = tsum;
    __syncthreads();
    for (int off = 1; off < 256; off <<= 1) {
        int xv = (t >= off) ? sh[t - off] : 0;
        __syncthreads();
        sh[t] += xv;
        __syncthreads();
    }
    int excl = sh[t] - tsum;
    if (base + 0 < n) { offsets[base + 0] = excl; cursor[base + 0] = excl; } excl += v0;
    if (base + 1 < n) { offsets[base + 1] = excl; cursor[base + 1] = excl; } excl += v1;
    if (base + 2 < n) { offsets[base + 2] = excl; cursor[base + 2] = excl; } excl += v2;
    if (base + 3 < n) { offsets[base + 3] = excl; cursor[base + 3] = excl; }
}

// Block-chunk reservation scatter into coarse buckets.
// Packed record: pk.x = col(17b) | rowlow(7b)<<17 ; pk.y = val bits.
__global__ __launch_bounds__(256) void bin_edges(
    const int* __restrict__ rows, const int* __restrict__ cols,
    const float* __restrict__ vals, int* __restrict__ cursor,
    int2* __restrict__ edata, int nedges, int nbuckets)
{
    __shared__ int lb[BMAX];
    const int t = threadIdx.x;
    const int per = (nedges + gridDim.x - 1) / gridDim.x;
    const int e0 = blockIdx.x * per;
    const int e1 = min(e0 + per, nedges);

    for (int i = t; i < nbuckets; i += 256) lb[i] = 0;
    __syncthreads();
    for (int e = e0 + t; e < e1; e += 256)
        atomicAdd(&lb[rows[e] >> BSHIFT], 1);
    __syncthreads();
    for (int i = t; i < nbuckets; i += 256) {
        int c = lb[i];
        lb[i] = c ? atomicAdd(&cursor[i], c) : 0;   // lb becomes block cursor
    }
    __syncthreads();
    for (int e = e0 + t; e < e1; e += 256) {
        const int r = rows[e];
        const int pos = atomicAdd(&lb[r >> BSHIFT], 1);
        int2 pk;
        pk.x = (cols[e] & 0x1FFFF) | ((r & 127) << 17);
        pk.y = __float_as_int(vals[e]);
        edata[pos] = pk;
    }
}

// ------------------------------------------------- per-bucket fine sort
__global__ __launch_bounds__(256) void fine_scatter(
    const int* __restrict__ offsets, const int* __restrict__ counts,
    int2* __restrict__ edata, int* __restrict__ foff, int* __restrict__ fcnt,
    int* __restrict__ bflag, int nrows)
{
    __shared__ int2 lrec[FCAP];      // 52 KB
    __shared__ int cnt[128];
    __shared__ int cur[128];
    __shared__ int sh[128];
    const int t = threadIdx.x;
    const int b = blockIdx.x;
    const int beg = offsets[b];
    const int cntE = counts[b];
    const int row0 = b << BSHIFT;

    if (t < 128) cnt[t] = 0;
    __syncthreads();

    if (cntE > FCAP) {
        if (t == 0) bflag[b] = 1;
        if (t < 128) {
            const int grow = row0 + t;
            if (grow < nrows) { foff[grow] = beg; fcnt[grow] = 0; }
        }
        return;
    }

    for (int k = t; k < cntE; k += 256) {
        int2 p = edata[beg + k];
        lrec[k] = p;
        atomicAdd(&cnt[(p.x >> 17) & 127], 1);
    }
    __syncthreads();

    if (t < 128) sh[t] = cnt[t];
    __syncthreads();
    for (int off = 1; off < 128; off <<= 1) {
        int xv = 0;
        if (t < 128 && t >= off) xv = sh[t - off];
        __syncthreads();
        if (t < 128) sh[t] += xv;
        __syncthreads();
    }
    if (t < 128) {
        const int excl = sh[t] - cnt[t];
        cur[t] = excl;
        const int grow = row0 + t;
        if (grow < nrows) { foff[grow] = beg + excl; fcnt[grow] = cnt[t]; }
    }
    __syncthreads();

    for (int k = t; k < cntE; k += 256) {
        const int2 p = lrec[k];
        const int rl = (p.x >> 17) & 127;
        const int pos = beg + atomicAdd(&cur[rl], 1);
        edata[pos] = make_int2(p.x & 0x1FFFF, p.y);
    }
}

// ---------------------------------------------------------- SpMM reduce
// One 16-lane group per row; lane owns 4 features. Register accumulate,
// 8-deep unroll for gather MLP.
__global__ __launch_bounds__(256) void spmm_reduce(
    const int* __restrict__ foff, const int* __restrict__ fcnt,
    const int2* __restrict__ edata, const float* __restrict__ support,
    float* __restrict__ out, int nrows)
{
    const int g = blockIdx.x * 16 + (threadIdx.x >> 4);
    const int f0 = (threadIdx.x & 15) * 4;
    if (g >= nrows) return;
    int e = foff[g];
    const int end = e + fcnt[g];
    float ax = 0.f, ay = 0.f, az = 0.f, aw = 0.f;

    for (; e + 8 <= end; e += 8) {
        int2 p[8];
        #pragma unroll
        for (int u = 0; u < 8; ++u) p[u] = edata[e + u];
        float4 s[8];
        #pragma unroll
        for (int u = 0; u < 8; ++u)
            s[u] = *reinterpret_cast<const float4*>(
                       &support[(size_t)p[u].x * MDIM + f0]);
        #pragma unroll
        for (int u = 0; u < 8; ++u) {
            const float v = __int_as_float(p[u].y);
            ax = fmaf(v, s[u].x, ax); ay = fmaf(v, s[u].y, ay);
            az = fmaf(v, s[u].z, az); aw = fmaf(v, s[u].w, aw);
        }
    }
    for (; e < end; ++e) {
        const int2 p = edata[e];
        const float v = __int_as_float(p.y);
        float4 s = *reinterpret_cast<const float4*>(
                       &support[(size_t)p.x * MDIM + f0]);
        ax = fmaf(v, s.x, ax); ay = fmaf(v, s.y, ay);
        az = fmaf(v, s.z, az); aw = fmaf(v, s.w, aw);
    }
    *reinterpret_cast<float4*>(&out[(size_t)g * MDIM + f0]) =
        make_float4(ax, ay, az, aw);
}

// --------------------------------------- oversized-bucket atomic tail
__global__ __launch_bounds__(256) void scatter_tail(
    const int* __restrict__ offsets, const int* __restrict__ counts,
    const int* __restrict__ bflag, const int2* __restrict__ edata,
    const float* __restrict__ support, float* __restrict__ out)
{
    const int b = blockIdx.x;
    if (!bflag[b]) return;
    const int beg = offsets[b];
    const int end = beg + counts[b];
    const int row0 = b << BSHIFT;
    const int g  = threadIdx.x >> 4;
    const int f0 = (threadIdx.x & 15) * 4;
    for (int e = beg + g; e < end; e += 16) {
        const int2 p = edata[e];
        const int c = p.x & 0x1FFFF;
        const int r = row0 + ((p.x >> 17) & 127);
        const float v = __int_as_float(p.y);
        float4 s = *reinterpret_cast<const float4*>(
                       &support[(size_t)c * MDIM + f0]);
        float* op = &out[(size_t)r * MDIM + f0];
        atomicAdd(op + 0, v * s.x);
        atomicAdd(op + 1, v * s.y);
        atomicAdd(op + 2, v * s.z);
        atomicAdd(op + 3, v * s.w);
    }
}

// ----------------------------------------------- fallback atomic scatter
__global__ __launch_bounds__(256) void scatter_edges(
    const int* __restrict__ rows, const int* __restrict__ cols,
    const float* __restrict__ vals, const float* __restrict__ support,
    float* __restrict__ out, int nedges)
{
    const int t = blockIdx.x * blockDim.x + threadIdx.x;
    const int fq = (t & 15) * 4;
    int e = t >> 4;
    const int estride = (gridDim.x * blockDim.x) >> 4;
    for (; e < nedges; e += estride) {
        const int r = rows[e];
        const int c = cols[e];
        const float v = vals[e];
        float4 s = *reinterpret_cast<const float4*>(
                       &support[(size_t)c * MDIM + fq]);
        float* op = &out[(size_t)r * MDIM + fq];
        atomicAdd(op + 0, v * s.x);
        atomicAdd(op + 1, v * s.y);
        atomicAdd(op + 2, v * s.z);
        atomicAdd(op + 3, v * s.w);
    }
}

// ---------------------------------------------------------------- launch
extern "C" void kernel_launch(void* const* d_in, const int* in_sizes, int n_in,
                              void* d_out, int out_size, void* d_ws, size_t ws_size,
                              hipStream_t stream) {
    const float* x    = (const float*)d_in[0];
    const int*   rows = (const int*)d_in[1];
    const int*   cols = (const int*)d_in[2];
    const float* vals = (const float*)d_in[3];
    const float* W    = (const float*)d_in[4];
    float* out = (float*)d_out;

    const int nnodes = in_sizes[0] / KDIM;   // 100000
    const int nedges = in_sizes[1];          // 1600000
    const int nbuckets = (nnodes + 127) >> BSHIFT;   // 782

    auto align256 = [](size_t v) { return (v + 255) & ~(size_t)255; };
    const size_t sz_support = align256((size_t)nnodes * MDIM * 4);
    const size_t sz_bkt     = align256((size_t)BMAX * 4);
    const size_t sz_nodes   = align256((size_t)nnodes * 4);
    const size_t sz_edata   = align256((size_t)nedges * 8);
    const size_t need = sz_support + 4 * sz_bkt + 2 * sz_nodes + sz_edata;

    char* w = (char*)d_ws;
    float* support = (float*)w;  w += sz_support;

    gemm_xw<<<dim3((nnodes + 255) / 256), dim3(256), 0, stream>>>(
        x, W, support, nnodes);

    // col packing needs nnodes <= 2^17; bucket tables need nbuckets <= BMAX.
    if (ws_size >= need && nbuckets <= BMAX && nnodes <= (1 << 17)) {
        int* counts  = (int*)w;  w += sz_bkt;
        int* offsets = (int*)w;  w += sz_bkt;
        int* cursor  = (int*)w;  w += sz_bkt;
        int* bflag   = (int*)w;  w += sz_bkt;
        int* foff    = (int*)w;  w += sz_nodes;
        int* fcnt    = (int*)w;  w += sz_nodes;
        int2* edata  = (int2*)w;

        hipMemsetAsync(counts, 0, (size_t)nbuckets * 4, stream);
        hipMemsetAsync(bflag, 0, (size_t)nbuckets * 4, stream);

        coarse_hist<<<dim3(256), dim3(256), 0, stream>>>(
            rows, counts, nedges, nbuckets);
        coarse_scan<<<dim3(1), dim3(256), 0, stream>>>(
            counts, offsets, cursor, nbuckets);
        bin_edges<<<dim3(256), dim3(256), 0, stream>>>(
            rows, cols, vals, cursor, edata, nedges, nbuckets);
        fine_scatter<<<dim3(nbuckets), dim3(256), 0, stream>>>(
            offsets, counts, edata, foff, fcnt, bflag, nnodes);
        spmm_reduce<<<dim3((nnodes + 15) / 16), dim3(256), 0, stream>>>(
            foff, fcnt, edata, support, out, nnodes);
        scatter_tail<<<dim3(nbuckets), dim3(256), 0, stream>>>(
            offsets, counts, bflag, edata, support, out);
    } else {
        hipMemsetAsync(d_out, 0, (size_t)out_size * sizeof(float), stream);
        scatter_edges<<<dim3(4096), dim3(256), 0, stream>>>(
            rows, cols, vals, support, out, nedges);
    }
}